// Round 16
// baseline (1931.946 us; speedup 1.0000x reference)
//
#include <hip/hip_runtime.h>
#include <hip/hip_bf16.h>
#include <stdint.h>

// GRU: B=256, S=512, E=256, H=512, C=128
// 16 teams x 16 WGs (tm = wg&15, cu = wg>>4). Team covers batch rows
// [16tm,16tm+16); member cu owns h dims [32cu,32cu+32). 4 waves/WG split the
// fused K=768 of [x_t | h] @ [W_ih|W_hh]^T; W slice in VGPRs (144/lane).
// Base = R14 (proven 1226us, absmax 0.0): wave-3 single-load poll (pipelined
// polls BANNED — R12 regalloc fault), direct h-frag gathers (R13), MALL
// atomic-swap protocol writes (R14: ack at MALL perform-point). R15's
// replicated flag lines REVERTED (falsified: flag line not contention-bound).
// R16 = R14 + ONE delta: LAST-DRAIN POST via LDS counter (R9-proven mech).
//  * Each wave vmcnt(0)-drains its OWN h stores, lane-0 ds_adds a monotone
//    LDS counter; the wave seeing old==4t+3 posts the team flag immediately.
//    Post fires at max(wave drains) instead of after barrier E + broadcast.
//  * Barrier E removed -> 2 barriers/step (A, D). cb WAR across rounds is
//    still ordered by bar A: any round-t+1 cb write happens after bar A(t+1),
//    which every wave reaches only after its round-t combine reads.
//  FP order identical => absmax stays 0.0.

typedef __attribute__((ext_vector_type(8))) short bf16x8;
typedef __attribute__((ext_vector_type(4))) float f32x4;

#define SWZ(r) (((r)&7) << 4)

static __device__ __forceinline__ unsigned short f2bf(float f) {
  unsigned x = __builtin_bit_cast(unsigned, f);
  return (unsigned short)((x + 0x7fffu + ((x >> 16) & 1u)) >> 16);  // RNE
}
static __device__ __forceinline__ float bf2f(unsigned u) {
  return __builtin_bit_cast(float, u << 16);
}
// Protocol write: returnless device-scope atomic swap — ack at MALL
// perform-point (~400cy earlier than store-through ack, R14-measured).
static __device__ __forceinline__ void st_mall_u32(void* p, unsigned v) {
  asm volatile("global_atomic_swap %0, %1, off" :: "v"(p), "v"(v) : "memory");
}
static __device__ __forceinline__ void ld_sys_u32(unsigned& d, const void* p) {
  asm volatile("global_load_dword %0, %1, off sc0 sc1" : "=v"(d) : "v"(p) : "memory");
}
static __device__ __forceinline__ bf16x8 cvt8(f32x4 a, f32x4 b) {
  bf16x8 r;
#pragma unroll
  for (int q = 0; q < 4; ++q) {
    r[q] = (short)f2bf(a[q]);
    r[4 + q] = (short)f2bf(b[q]);
  }
  return r;
}

__global__ __launch_bounds__(256, 1) void gru_persistent(
    const float* __restrict__ x, const float* __restrict__ h0,
    const float* __restrict__ Wih, const float* __restrict__ Whh,
    const float* __restrict__ bih, const float* __restrict__ bhh,
    unsigned* __restrict__ flags, unsigned short* __restrict__ hbuf) {
  __shared__ __align__(16) float cb[4 * 4 * 2 * 256];  // [wave][type][nf][row*16+col]
  __shared__ unsigned scnt;  // monotone drain counter (4 adds per step)

  const int tid = threadIdx.x, wg = blockIdx.x;
  const int tm = wg & 15, cu = wg >> 4;
  const int wv = tid >> 6, ln = tid & 63;
  const int bm = tm << 4;   // batch base
  const int d0 = cu << 5;   // h-dim slice base (32 dims)

  unsigned* tfl = flags + tm * 32;       // 16 flags on one 64B line; teams 128B apart
  const unsigned* fp = tfl + (ln & 15);
  char* hs0 = (char*)hbuf + (size_t)tm * 16384;
  char* hs1 = (char*)hbuf + 262144 + (size_t)tm * 16384;

  if (tid == 0) scnt = 0;  // visible WG-wide after E0

  // ---- W slice -> VGPR bf16 B-frags (once); frag f: 0-1 = x-part, 2-5 = h-part ----
  bf16x8 BF[3][2][6];
  {
    const int j = ln & 15, kgw = ln >> 4;
#pragma unroll
    for (int g = 0; g < 3; ++g)
#pragma unroll
      for (int nf = 0; nf < 2; ++nf)
#pragma unroll
        for (int f = 0; f < 6; ++f) {
          const int R = g * 512 + d0 + nf * 16 + j;
          const float* src;
          if (f < 2) src = Wih + (size_t)R * 256 + (64 * wv + 32 * f + 8 * kgw);
          else       src = Whh + (size_t)R * 512 + (128 * wv + 32 * (f - 2) + 8 * kgw);
          bf16x8 v;
#pragma unroll
          for (int i = 0; i < 8; ++i) v[i] = (short)f2bf(src[i]);
          BF[g][nf][f] = v;
        }
  }

  const int dl = tid & 15, rr = tid >> 4;
  const int dd0 = d0 + dl, dd1 = d0 + 16 + dl;
  const float bR0 = bih[dd0] + bhh[dd0], bR1 = bih[dd1] + bhh[dd1];
  const float bZ0 = bih[512 + dd0] + bhh[512 + dd0], bZ1 = bih[512 + dd1] + bhh[512 + dd1];
  const float bNx0 = bih[1024 + dd0], bNx1 = bih[1024 + dd1];
  const float bNh0 = bhh[1024 + dd0], bNh1 = bhh[1024 + dd1];

  float hr0 = h0[(size_t)(bm + rr) * 512 + dd0];
  float hr1 = h0[(size_t)(bm + rr) * 512 + dd1];

  // ---- gather geometry (loop-invariant): lane covers A-row (ln&15), k-chunk kg ----
  const int grow = ln & 15, kg = ln >> 4;
  const int gof0 = grow * 1024 + ((256 * wv + 0 + 16 * kg) ^ SWZ(grow));
  const int gof1 = grow * 1024 + ((256 * wv + 64 + 16 * kg) ^ SWZ(grow));
  const int gof2 = grow * 1024 + ((256 * wv + 128 + 16 * kg) ^ SWZ(grow));
  const int gof3 = grow * 1024 + ((256 * wv + 192 + 16 * kg) ^ SWZ(grow));
  // x frag base: row (bm+grow), floats [64wv+8kg .. ) ; frag fx adds 32*fx
  const float* xlane = x + (size_t)(bm + grow) * 512 * 256 + 64 * wv + 8 * kg;

  // ---- prologue: h(0) -> slot0 (MALL writes); x(0) -> regs -> bf16 frags ----
  {
    unsigned a0 = f2bf(hr0), a1 = f2bf(hr1);
    unsigned p0 = __shfl_xor(a0, 1, 64), p1 = __shfl_xor(a1, 1, 64);
    if (!(dl & 1)) {
      st_mall_u32(hs0 + rr * 1024 + ((2 * dd0) ^ SWZ(rr)), a0 | (p0 << 16));
      st_mall_u32(hs0 + rr * 1024 + ((2 * dd1) ^ SWZ(rr)), a1 | (p1 << 16));
    }
  }
  f32x4 xn0a = *(const f32x4*)(xlane + 0);
  f32x4 xn0b = *(const f32x4*)(xlane + 4);
  f32x4 xn1a = *(const f32x4*)(xlane + 32);
  f32x4 xn1b = *(const f32x4*)(xlane + 36);
  bf16x8 xf0 = cvt8(xn0a, xn0b);
  bf16x8 xf1 = cvt8(xn1a, xn1b);

  asm volatile("s_waitcnt vmcnt(0)" ::: "memory");  // h0 writes performed at MALL
  __syncthreads();                                  // E0: acks + scnt init visible
  if (tid == 192) st_mall_u32(tfl + cu, 1u);        // certify h(0)
  unsigned fv = 0;
  if (wv == 3) ld_sys_u32(fv, fp);                  // prime first poll

  for (int t = 0; t < 512; ++t) {
    const unsigned tgt = (unsigned)(t + 1);
    f32x4 aR[2] = {}, aZ[2] = {}, aNx[2] = {}, aNh[2] = {};

    // x-part MFMA from register frags (per-acc order fx0 then fx1 — R13-identical)
#define XPART()                                                                          \
  {                                                                                      \
    _Pragma("unroll")                                                                    \
    for (int nf = 0; nf < 2; ++nf) {                                                     \
      aR[nf]  = __builtin_amdgcn_mfma_f32_16x16x32_bf16(xf0, BF[0][nf][0], aR[nf], 0, 0, 0);  \
      aZ[nf]  = __builtin_amdgcn_mfma_f32_16x16x32_bf16(xf0, BF[1][nf][0], aZ[nf], 0, 0, 0);  \
      aNx[nf] = __builtin_amdgcn_mfma_f32_16x16x32_bf16(xf0, BF[2][nf][0], aNx[nf], 0, 0, 0); \
      aR[nf]  = __builtin_amdgcn_mfma_f32_16x16x32_bf16(xf1, BF[0][nf][1], aR[nf], 0, 0, 0);  \
      aZ[nf]  = __builtin_amdgcn_mfma_f32_16x16x32_bf16(xf1, BF[1][nf][1], aZ[nf], 0, 0, 0);  \
      aNx[nf] = __builtin_amdgcn_mfma_f32_16x16x32_bf16(xf1, BF[2][nf][1], aNx[nf], 0, 0, 0); \
    }                                                                                    \
  }

    if (wv == 3) {
      // single-load poll (R10-proven; drain prime, then load+wait per round)
      asm volatile("s_waitcnt vmcnt(0)" : "+v"(fv) :: "memory");
      while (__ballot(fv >= tgt) != ~0ull) {
        asm volatile("global_load_dword %0, %1, off sc0 sc1\n\ts_waitcnt vmcnt(0)"
                     : "=v"(fv) : "v"(fp) : "memory");
      }
    } else {
      XPART();  // waves 0-2: x-MFMA under the poll
    }
    __syncthreads();  // A: h(t) certified for the whole WG

    // ---- direct h-frag gathers (device-scope): regs, no LDS hop ----
    const char* hsrc = (t & 1) ? hs1 : hs0;
    f32x4 g0, g1, g2, g3;
    asm volatile("global_load_dwordx4 %0, %1, off sc0 sc1"
                 : "=v"(g0) : "v"(hsrc + gof0) : "memory");
    asm volatile("global_load_dwordx4 %0, %1, off sc0 sc1"
                 : "=v"(g1) : "v"(hsrc + gof1) : "memory");
    asm volatile("global_load_dwordx4 %0, %1, off sc0 sc1"
                 : "=v"(g2) : "v"(hsrc + gof2) : "memory");
    asm volatile("global_load_dwordx4 %0, %1, off sc0 sc1"
                 : "=v"(g3) : "v"(hsrc + gof3) : "memory");

    if (wv == 3) { XPART(); }  // wave 3: x-MFMA under its own gather RT
    __builtin_amdgcn_sched_barrier(0);  // pin x-MFMA BEFORE the drain

    asm volatile("s_waitcnt vmcnt(0)"
                 : "+v"(g0), "+v"(g1), "+v"(g2), "+v"(g3) :: "memory");
    const bf16x8 hf0 = __builtin_bit_cast(bf16x8, g0);
    const bf16x8 hf1 = __builtin_bit_cast(bf16x8, g1);
    const bf16x8 hf2 = __builtin_bit_cast(bf16x8, g2);
    const bf16x8 hf3 = __builtin_bit_cast(bf16x8, g3);

    // x(t+1) prefetch (plain loads; compiler-managed waits; consumed at tail cvt)
    if (t + 1 < 512) {
      const float* xb2 = xlane + (size_t)(t + 1) * 256;
      xn0a = *(const f32x4*)(xb2 + 0);
      xn0b = *(const f32x4*)(xb2 + 4);
      xn1a = *(const f32x4*)(xb2 + 32);
      xn1b = *(const f32x4*)(xb2 + 36);
    }

    // ---- h-part MFMA (4 frags, register operands; per-acc order fh0..3) ----
#pragma unroll
    for (int nf = 0; nf < 2; ++nf) {
      aR[nf]  = __builtin_amdgcn_mfma_f32_16x16x32_bf16(hf0, BF[0][nf][2], aR[nf], 0, 0, 0);
      aZ[nf]  = __builtin_amdgcn_mfma_f32_16x16x32_bf16(hf0, BF[1][nf][2], aZ[nf], 0, 0, 0);
      aNh[nf] = __builtin_amdgcn_mfma_f32_16x16x32_bf16(hf0, BF[2][nf][2], aNh[nf], 0, 0, 0);
      aR[nf]  = __builtin_amdgcn_mfma_f32_16x16x32_bf16(hf1, BF[0][nf][3], aR[nf], 0, 0, 0);
      aZ[nf]  = __builtin_amdgcn_mfma_f32_16x16x32_bf16(hf1, BF[1][nf][3], aZ[nf], 0, 0, 0);
      aNh[nf] = __builtin_amdgcn_mfma_f32_16x16x32_bf16(hf1, BF[2][nf][3], aNh[nf], 0, 0, 0);
      aR[nf]  = __builtin_amdgcn_mfma_f32_16x16x32_bf16(hf2, BF[0][nf][4], aR[nf], 0, 0, 0);
      aZ[nf]  = __builtin_amdgcn_mfma_f32_16x16x32_bf16(hf2, BF[1][nf][4], aZ[nf], 0, 0, 0);
      aNh[nf] = __builtin_amdgcn_mfma_f32_16x16x32_bf16(hf2, BF[2][nf][4], aNh[nf], 0, 0, 0);
      aR[nf]  = __builtin_amdgcn_mfma_f32_16x16x32_bf16(hf3, BF[0][nf][5], aR[nf], 0, 0, 0);
      aZ[nf]  = __builtin_amdgcn_mfma_f32_16x16x32_bf16(hf3, BF[1][nf][5], aZ[nf], 0, 0, 0);
      aNh[nf] = __builtin_amdgcn_mfma_f32_16x16x32_bf16(hf3, BF[2][nf][5], aNh[nf], 0, 0, 0);
    }

    // ---- partials -> cbuf (identical R13) ----
    {
      const int cc = ln & 15, cg = ln >> 4;
#pragma unroll
      for (int nf = 0; nf < 2; ++nf)
#pragma unroll
        for (int i = 0; i < 4; ++i) {
          const int row = cg * 4 + i;
          cb[((wv * 4 + 0) * 2 + nf) * 256 + row * 16 + cc] = aR[nf][i];
          cb[((wv * 4 + 1) * 2 + nf) * 256 + row * 16 + cc] = aZ[nf][i];
          cb[((wv * 4 + 2) * 2 + nf) * 256 + row * 16 + cc] = aNx[nf][i];
          cb[((wv * 4 + 3) * 2 + nf) * 256 + row * 16 + cc] = aNh[nf][i];
        }
    }
    __syncthreads();  // D

    // ---- combine + gates (fp32, identical R13) ----
    {
#define CBX(w, ty, nf) cb[(((w) * 4 + (ty)) * 2 + (nf)) * 256 + rr * 16 + dl]
      float rp0 = bR0 + CBX(0,0,0) + CBX(1,0,0) + CBX(2,0,0) + CBX(3,0,0);
      float rp1 = bR1 + CBX(0,0,1) + CBX(1,0,1) + CBX(2,0,1) + CBX(3,0,1);
      float zp0 = bZ0 + CBX(0,1,0) + CBX(1,1,0) + CBX(2,1,0) + CBX(3,1,0);
      float zp1 = bZ1 + CBX(0,1,1) + CBX(1,1,1) + CBX(2,1,1) + CBX(3,1,1);
      float ix0 = bNx0 + CBX(0,2,0) + CBX(1,2,0) + CBX(2,2,0) + CBX(3,2,0);
      float ix1 = bNx1 + CBX(0,2,1) + CBX(1,2,1) + CBX(2,2,1) + CBX(3,2,1);
      float hn0 = bNh0 + CBX(0,3,0) + CBX(1,3,0) + CBX(2,3,0) + CBX(3,3,0);
      float hn1 = bNh1 + CBX(0,3,1) + CBX(1,3,1) + CBX(2,3,1) + CBX(3,3,1);
#undef CBX
      const float rg0 = 1.f / (1.f + __expf(-rp0)), rg1 = 1.f / (1.f + __expf(-rp1));
      const float zg0 = 1.f / (1.f + __expf(-zp0)), zg1 = 1.f / (1.f + __expf(-zp1));
      const float e0 = __expf(2.f * (ix0 + rg0 * hn0));
      const float e1 = __expf(2.f * (ix1 + rg1 * hn1));
      const float ng0 = 1.f - 2.f / (e0 + 1.f), ng1 = 1.f - 2.f / (e1 + 1.f);
      hr0 = ng0 + zg0 * (hr0 - ng0);
      hr1 = ng1 + zg1 * (hr1 - ng1);
    }

    // ---- h(t+1) -> hbuf (MALL atomic writes) ----
    {
      char* hdst = ((t + 1) & 1) ? hs1 : hs0;
      unsigned a0 = f2bf(hr0), a1 = f2bf(hr1);
      unsigned p0 = __shfl_xor(a0, 1, 64), p1 = __shfl_xor(a1, 1, 64);
      if (!(dl & 1)) {
        st_mall_u32(hdst + rr * 1024 + ((2 * dd0) ^ SWZ(rr)), a0 | (p0 << 16));
        st_mall_u32(hdst + rr * 1024 + ((2 * dd1) ^ SWZ(rr)), a1 | (p1 << 16));
      }
    }
    // cvt x(t+1) frags in the ack shadow (compiler waits on the plain loads)
    if (t + 1 < 512) {
      xf0 = cvt8(xn0a, xn0b);
      xf1 = cvt8(xn1a, xn1b);
    }
    asm volatile("s_waitcnt vmcnt(0)" ::: "memory");  // THIS wave's h writes at MALL
    // last-drained wave posts the team flag (all 4 waves' stores performed)
    if (ln == 0) {
      unsigned oldv = __hip_atomic_fetch_add(&scnt, 1u, __ATOMIC_RELAXED,
                                             __HIP_MEMORY_SCOPE_WORKGROUP);
      if (oldv == 4u * (unsigned)t + 3u) st_mall_u32(tfl + cu, tgt + 1u);
    }
    if (wv == 3) ld_sys_u32(fv, fp);  // prime next poll
    // no barrier E: bar A(t+1) orders next round's cb writes after combine(t)
  }
#undef XPART
}

// ---- logits + masked CE + accuracy; one WG per batch row ----
__global__ __launch_bounds__(128) void logits_loss(
    const unsigned short* __restrict__ hbuf, const float* __restrict__ Wout,
    const float* __restrict__ bout, const int* __restrict__ label,
    float* __restrict__ accv) {
  __shared__ float hrow[512];
  __shared__ float lg[128];
  const int b = blockIdx.x;
  const int tm = b >> 4, r = b & 15;
  const char* base = (const char*)hbuf + (size_t)tm * 16384 + r * 1024;
  for (int i = threadIdx.x; i < 256; i += 128) {
    const char* p = base + ((i * 4) ^ SWZ(r));
    unsigned v;
    asm volatile("global_load_dword %0, %1, off sc0 sc1\n\ts_waitcnt vmcnt(0)"
                 : "=v"(v) : "v"(p) : "memory");
    hrow[2 * i] = bf2f(v & 0xffffu);
    hrow[2 * i + 1] = bf2f(v >> 16);
  }
  __syncthreads();
  const int c = threadIdx.x;
  const f32x4* w4 = (const f32x4*)(Wout + (size_t)c * 512);
  const f32x4* h4 = (const f32x4*)hrow;
  float s = bout[c];
#pragma unroll 4
  for (int i = 0; i < 128; ++i) {
    f32x4 wv = w4[i], hv = h4[i];
    s += wv[0] * hv[0] + wv[1] * hv[1] + wv[2] * hv[2] + wv[3] * hv[3];
  }
  lg[c] = s;
  __syncthreads();
  if (c == 0) {
    float mx = lg[0];
    int am = 0;
    for (int i = 1; i < 128; ++i)
      if (lg[i] > mx) { mx = lg[i]; am = i; }
    float se = 0.f;
    for (int i = 0; i < 128; ++i) se += __expf(lg[i] - mx);
    const int lb = label[b];
    const float logp = lg[lb] - mx - __logf(se);
    if (lb != 0) {
      atomicAdd(&accv[0], -logp);
      atomicAdd(&accv[1], 1.0f);
    }
    if (am == lb) atomicAdd(&accv[2], 1.0f);
  }
}

__global__ void finalize_k(const float* __restrict__ accv, float* __restrict__ out) {
  out[0] = accv[0] / fmaxf(accv[1], 1.0f);
  out[1] = accv[2] * (1.0f / 256.0f);
}

extern "C" void kernel_launch(void* const* d_in, const int* in_sizes, int n_in,
                              void* d_out, int out_size, void* d_ws, size_t ws_size,
                              hipStream_t stream) {
  (void)in_sizes; (void)n_in; (void)out_size; (void)ws_size;
  const float* x = (const float*)d_in[0];
  const int* label = (const int*)d_in[1];
  const float* h0 = (const float*)d_in[2];
  const float* Wih = (const float*)d_in[3];
  const float* Whh = (const float*)d_in[4];
  const float* bih = (const float*)d_in[5];
  const float* bhh = (const float*)d_in[6];
  const float* Wout = (const float*)d_in[7];
  const float* bout = (const float*)d_in[8];
  float* out = (float*)d_out;

  char* ws = (char*)d_ws;
  unsigned* flags = (unsigned*)ws;                      // 16 teams x 32 u32 (16 used)
  float* accv = (float*)(ws + 4096);                    // 3 accumulators
  unsigned short* hbuf = (unsigned short*)(ws + 8192);  // 2 slots x 16 teams x 16 KB

  hipMemsetAsync(ws, 0, 8192, stream);  // flags + accv: deterministic per call

  gru_persistent<<<dim3(256), dim3(256), 0, stream>>>(x, h0, Wih, Whh, bih, bhh,
                                                      flags, hbuf);
  logits_loss<<<dim3(256), dim3(128), 0, stream>>>(hbuf, Wout, bout, label, accv);
  finalize_k<<<dim3(1), dim3(1), 0, stream>>>(accv, out);
}

// Round 17
// 1235.882 us; speedup vs baseline: 1.5632x; 1.5632x over previous
//
#include <hip/hip_runtime.h>
#include <hip/hip_bf16.h>
#include <stdint.h>

// GRU: B=256, S=512, E=256, H=512, C=128
// 16 teams x 16 WGs (tm = wg&15, cu = wg>>4). Team covers batch rows
// [16tm,16tm+16); member cu owns h dims [32cu,32cu+32). 4 waves/WG split the
// fused K=768 of [x_t | h] @ [W_ih|W_hh]^T; W slice in VGPRs (144/lane).
// Base = R14 EXACTLY (proven 1226us, absmax 0.0): wave-3 single-load poll
// (pipelined polls BANNED — R12 regalloc fault), barriers A/D/E (barE is
// load-bearing — R16 falsified its removal), direct h-frag gathers (R13),
// MALL atomic-swap protocol writes (R14). R15 (replicated flags) and R16
// (LDS-counter post) both falsified and reverted.
// R17 = R14 + ONE delta: OWN-FLAG SKIP in the poll.
//  * Our own WG's flag check is redundant: our stores are drained by the
//    pre-barE vmcnt(0) in every wave, and barE orders them before our
//    gathers (issued after the next barA) — own-slice safety is program
//    order, not the flag. The own-flag check is also the worst-conditioned:
//    the prime is issued ~5cy after our own post (coin-flip race at MALL),
//    forcing an extra full poll round ~half the time. Skip lanes where
//    (ln&15)==cu. We still POST the flag (other teams' WGs read it).
//  FP order identical => absmax stays 0.0.

typedef __attribute__((ext_vector_type(8))) short bf16x8;
typedef __attribute__((ext_vector_type(4))) float f32x4;

#define SWZ(r) (((r)&7) << 4)

static __device__ __forceinline__ unsigned short f2bf(float f) {
  unsigned x = __builtin_bit_cast(unsigned, f);
  return (unsigned short)((x + 0x7fffu + ((x >> 16) & 1u)) >> 16);  // RNE
}
static __device__ __forceinline__ float bf2f(unsigned u) {
  return __builtin_bit_cast(float, u << 16);
}
// Protocol write: returnless device-scope atomic swap — ack at MALL
// perform-point (~400cy earlier than store-through ack, R14-measured).
static __device__ __forceinline__ void st_mall_u32(void* p, unsigned v) {
  asm volatile("global_atomic_swap %0, %1, off" :: "v"(p), "v"(v) : "memory");
}
static __device__ __forceinline__ void ld_sys_u32(unsigned& d, const void* p) {
  asm volatile("global_load_dword %0, %1, off sc0 sc1" : "=v"(d) : "v"(p) : "memory");
}
static __device__ __forceinline__ bf16x8 cvt8(f32x4 a, f32x4 b) {
  bf16x8 r;
#pragma unroll
  for (int q = 0; q < 4; ++q) {
    r[q] = (short)f2bf(a[q]);
    r[4 + q] = (short)f2bf(b[q]);
  }
  return r;
}

__global__ __launch_bounds__(256, 1) void gru_persistent(
    const float* __restrict__ x, const float* __restrict__ h0,
    const float* __restrict__ Wih, const float* __restrict__ Whh,
    const float* __restrict__ bih, const float* __restrict__ bhh,
    unsigned* __restrict__ flags, unsigned short* __restrict__ hbuf) {
  __shared__ __align__(16) float cb[4 * 4 * 2 * 256];  // [wave][type][nf][row*16+col]

  const int tid = threadIdx.x, wg = blockIdx.x;
  const int tm = wg & 15, cu = wg >> 4;
  const int wv = tid >> 6, ln = tid & 63;
  const int bm = tm << 4;   // batch base
  const int d0 = cu << 5;   // h-dim slice base (32 dims)

  unsigned* tfl = flags + tm * 32;       // 16 flags on one 64B line; teams 128B apart
  const unsigned* fp = tfl + (ln & 15);
  char* hs0 = (char*)hbuf + (size_t)tm * 16384;
  char* hs1 = (char*)hbuf + 262144 + (size_t)tm * 16384;

  // ---- W slice -> VGPR bf16 B-frags (once); frag f: 0-1 = x-part, 2-5 = h-part ----
  bf16x8 BF[3][2][6];
  {
    const int j = ln & 15, kgw = ln >> 4;
#pragma unroll
    for (int g = 0; g < 3; ++g)
#pragma unroll
      for (int nf = 0; nf < 2; ++nf)
#pragma unroll
        for (int f = 0; f < 6; ++f) {
          const int R = g * 512 + d0 + nf * 16 + j;
          const float* src;
          if (f < 2) src = Wih + (size_t)R * 256 + (64 * wv + 32 * f + 8 * kgw);
          else       src = Whh + (size_t)R * 512 + (128 * wv + 32 * (f - 2) + 8 * kgw);
          bf16x8 v;
#pragma unroll
          for (int i = 0; i < 8; ++i) v[i] = (short)f2bf(src[i]);
          BF[g][nf][f] = v;
        }
  }

  const int dl = tid & 15, rr = tid >> 4;
  const int dd0 = d0 + dl, dd1 = d0 + 16 + dl;
  const float bR0 = bih[dd0] + bhh[dd0], bR1 = bih[dd1] + bhh[dd1];
  const float bZ0 = bih[512 + dd0] + bhh[512 + dd0], bZ1 = bih[512 + dd1] + bhh[512 + dd1];
  const float bNx0 = bih[1024 + dd0], bNx1 = bih[1024 + dd1];
  const float bNh0 = bhh[1024 + dd0], bNh1 = bhh[1024 + dd1];

  float hr0 = h0[(size_t)(bm + rr) * 512 + dd0];
  float hr1 = h0[(size_t)(bm + rr) * 512 + dd1];

  // ---- gather geometry (loop-invariant): lane covers A-row (ln&15), k-chunk kg ----
  const int grow = ln & 15, kg = ln >> 4;
  const int gof0 = grow * 1024 + ((256 * wv + 0 + 16 * kg) ^ SWZ(grow));
  const int gof1 = grow * 1024 + ((256 * wv + 64 + 16 * kg) ^ SWZ(grow));
  const int gof2 = grow * 1024 + ((256 * wv + 128 + 16 * kg) ^ SWZ(grow));
  const int gof3 = grow * 1024 + ((256 * wv + 192 + 16 * kg) ^ SWZ(grow));
  // x frag base: row (bm+grow), floats [64wv+8kg .. ) ; frag fx adds 32*fx
  const float* xlane = x + (size_t)(bm + grow) * 512 * 256 + 64 * wv + 8 * kg;

  // ---- prologue: h(0) -> slot0 (MALL writes); x(0) -> regs -> bf16 frags ----
  {
    unsigned a0 = f2bf(hr0), a1 = f2bf(hr1);
    unsigned p0 = __shfl_xor(a0, 1, 64), p1 = __shfl_xor(a1, 1, 64);
    if (!(dl & 1)) {
      st_mall_u32(hs0 + rr * 1024 + ((2 * dd0) ^ SWZ(rr)), a0 | (p0 << 16));
      st_mall_u32(hs0 + rr * 1024 + ((2 * dd1) ^ SWZ(rr)), a1 | (p1 << 16));
    }
  }
  f32x4 xn0a = *(const f32x4*)(xlane + 0);
  f32x4 xn0b = *(const f32x4*)(xlane + 4);
  f32x4 xn1a = *(const f32x4*)(xlane + 32);
  f32x4 xn1b = *(const f32x4*)(xlane + 36);
  bf16x8 xf0 = cvt8(xn0a, xn0b);
  bf16x8 xf1 = cvt8(xn1a, xn1b);

  asm volatile("s_waitcnt vmcnt(0)" ::: "memory");  // h0 writes performed at MALL
  __syncthreads();                                  // E0
  if (tid == 192) st_mall_u32(tfl + cu, 1u);        // certify h(0)
  unsigned fv = 0;
  if (wv == 3) ld_sys_u32(fv, fp);                  // prime first poll

  for (int t = 0; t < 512; ++t) {
    const unsigned tgt = (unsigned)(t + 1);
    f32x4 aR[2] = {}, aZ[2] = {}, aNx[2] = {}, aNh[2] = {};

    // x-part MFMA from register frags (per-acc order fx0 then fx1 — R13-identical)
#define XPART()                                                                          \
  {                                                                                      \
    _Pragma("unroll")                                                                    \
    for (int nf = 0; nf < 2; ++nf) {                                                     \
      aR[nf]  = __builtin_amdgcn_mfma_f32_16x16x32_bf16(xf0, BF[0][nf][0], aR[nf], 0, 0, 0);  \
      aZ[nf]  = __builtin_amdgcn_mfma_f32_16x16x32_bf16(xf0, BF[1][nf][0], aZ[nf], 0, 0, 0);  \
      aNx[nf] = __builtin_amdgcn_mfma_f32_16x16x32_bf16(xf0, BF[2][nf][0], aNx[nf], 0, 0, 0); \
      aR[nf]  = __builtin_amdgcn_mfma_f32_16x16x32_bf16(xf1, BF[0][nf][1], aR[nf], 0, 0, 0);  \
      aZ[nf]  = __builtin_amdgcn_mfma_f32_16x16x32_bf16(xf1, BF[1][nf][1], aZ[nf], 0, 0, 0);  \
      aNx[nf] = __builtin_amdgcn_mfma_f32_16x16x32_bf16(xf1, BF[2][nf][1], aNx[nf], 0, 0, 0); \
    }                                                                                    \
  }

    if (wv == 3) {
      // single-load poll (R10-proven) with OWN-FLAG SKIP: lane (ln&15)==cu is
      // satisfied by program order (pre-barE vmcnt(0) + barE precede gathers).
      asm volatile("s_waitcnt vmcnt(0)" : "+v"(fv) :: "memory");
      while (__ballot(fv >= tgt || (ln & 15) == cu) != ~0ull) {
        asm volatile("global_load_dword %0, %1, off sc0 sc1\n\ts_waitcnt vmcnt(0)"
                     : "=v"(fv) : "v"(fp) : "memory");
      }
    } else {
      XPART();  // waves 0-2: x-MFMA under the poll
    }
    __syncthreads();  // A: h(t) certified for the whole WG

    // ---- direct h-frag gathers (device-scope): regs, no LDS hop ----
    const char* hsrc = (t & 1) ? hs1 : hs0;
    f32x4 g0, g1, g2, g3;
    asm volatile("global_load_dwordx4 %0, %1, off sc0 sc1"
                 : "=v"(g0) : "v"(hsrc + gof0) : "memory");
    asm volatile("global_load_dwordx4 %0, %1, off sc0 sc1"
                 : "=v"(g1) : "v"(hsrc + gof1) : "memory");
    asm volatile("global_load_dwordx4 %0, %1, off sc0 sc1"
                 : "=v"(g2) : "v"(hsrc + gof2) : "memory");
    asm volatile("global_load_dwordx4 %0, %1, off sc0 sc1"
                 : "=v"(g3) : "v"(hsrc + gof3) : "memory");

    if (wv == 3) { XPART(); }  // wave 3: x-MFMA under its own gather RT
    __builtin_amdgcn_sched_barrier(0);  // pin x-MFMA BEFORE the drain

    asm volatile("s_waitcnt vmcnt(0)"
                 : "+v"(g0), "+v"(g1), "+v"(g2), "+v"(g3) :: "memory");
    const bf16x8 hf0 = __builtin_bit_cast(bf16x8, g0);
    const bf16x8 hf1 = __builtin_bit_cast(bf16x8, g1);
    const bf16x8 hf2 = __builtin_bit_cast(bf16x8, g2);
    const bf16x8 hf3 = __builtin_bit_cast(bf16x8, g3);

    // x(t+1) prefetch (plain loads; compiler-managed waits; consumed at tail cvt)
    if (t + 1 < 512) {
      const float* xb2 = xlane + (size_t)(t + 1) * 256;
      xn0a = *(const f32x4*)(xb2 + 0);
      xn0b = *(const f32x4*)(xb2 + 4);
      xn1a = *(const f32x4*)(xb2 + 32);
      xn1b = *(const f32x4*)(xb2 + 36);
    }

    // ---- h-part MFMA (4 frags, register operands; per-acc order fh0..3) ----
#pragma unroll
    for (int nf = 0; nf < 2; ++nf) {
      aR[nf]  = __builtin_amdgcn_mfma_f32_16x16x32_bf16(hf0, BF[0][nf][2], aR[nf], 0, 0, 0);
      aZ[nf]  = __builtin_amdgcn_mfma_f32_16x16x32_bf16(hf0, BF[1][nf][2], aZ[nf], 0, 0, 0);
      aNh[nf] = __builtin_amdgcn_mfma_f32_16x16x32_bf16(hf0, BF[2][nf][2], aNh[nf], 0, 0, 0);
      aR[nf]  = __builtin_amdgcn_mfma_f32_16x16x32_bf16(hf1, BF[0][nf][3], aR[nf], 0, 0, 0);
      aZ[nf]  = __builtin_amdgcn_mfma_f32_16x16x32_bf16(hf1, BF[1][nf][3], aZ[nf], 0, 0, 0);
      aNh[nf] = __builtin_amdgcn_mfma_f32_16x16x32_bf16(hf1, BF[2][nf][3], aNh[nf], 0, 0, 0);
      aR[nf]  = __builtin_amdgcn_mfma_f32_16x16x32_bf16(hf2, BF[0][nf][4], aR[nf], 0, 0, 0);
      aZ[nf]  = __builtin_amdgcn_mfma_f32_16x16x32_bf16(hf2, BF[1][nf][4], aZ[nf], 0, 0, 0);
      aNh[nf] = __builtin_amdgcn_mfma_f32_16x16x32_bf16(hf2, BF[2][nf][4], aNh[nf], 0, 0, 0);
      aR[nf]  = __builtin_amdgcn_mfma_f32_16x16x32_bf16(hf3, BF[0][nf][5], aR[nf], 0, 0, 0);
      aZ[nf]  = __builtin_amdgcn_mfma_f32_16x16x32_bf16(hf3, BF[1][nf][5], aZ[nf], 0, 0, 0);
      aNh[nf] = __builtin_amdgcn_mfma_f32_16x16x32_bf16(hf3, BF[2][nf][5], aNh[nf], 0, 0, 0);
    }

    // ---- partials -> cbuf (identical R13) ----
    {
      const int cc = ln & 15, cg = ln >> 4;
#pragma unroll
      for (int nf = 0; nf < 2; ++nf)
#pragma unroll
        for (int i = 0; i < 4; ++i) {
          const int row = cg * 4 + i;
          cb[((wv * 4 + 0) * 2 + nf) * 256 + row * 16 + cc] = aR[nf][i];
          cb[((wv * 4 + 1) * 2 + nf) * 256 + row * 16 + cc] = aZ[nf][i];
          cb[((wv * 4 + 2) * 2 + nf) * 256 + row * 16 + cc] = aNx[nf][i];
          cb[((wv * 4 + 3) * 2 + nf) * 256 + row * 16 + cc] = aNh[nf][i];
        }
    }
    __syncthreads();  // D

    // ---- combine + gates (fp32, identical R13) ----
    {
#define CBX(w, ty, nf) cb[(((w) * 4 + (ty)) * 2 + (nf)) * 256 + rr * 16 + dl]
      float rp0 = bR0 + CBX(0,0,0) + CBX(1,0,0) + CBX(2,0,0) + CBX(3,0,0);
      float rp1 = bR1 + CBX(0,0,1) + CBX(1,0,1) + CBX(2,0,1) + CBX(3,0,1);
      float zp0 = bZ0 + CBX(0,1,0) + CBX(1,1,0) + CBX(2,1,0) + CBX(3,1,0);
      float zp1 = bZ1 + CBX(0,1,1) + CBX(1,1,1) + CBX(2,1,1) + CBX(3,1,1);
      float ix0 = bNx0 + CBX(0,2,0) + CBX(1,2,0) + CBX(2,2,0) + CBX(3,2,0);
      float ix1 = bNx1 + CBX(0,2,1) + CBX(1,2,1) + CBX(2,2,1) + CBX(3,2,1);
      float hn0 = bNh0 + CBX(0,3,0) + CBX(1,3,0) + CBX(2,3,0) + CBX(3,3,0);
      float hn1 = bNh1 + CBX(0,3,1) + CBX(1,3,1) + CBX(2,3,1) + CBX(3,3,1);
#undef CBX
      const float rg0 = 1.f / (1.f + __expf(-rp0)), rg1 = 1.f / (1.f + __expf(-rp1));
      const float zg0 = 1.f / (1.f + __expf(-zp0)), zg1 = 1.f / (1.f + __expf(-zp1));
      const float e0 = __expf(2.f * (ix0 + rg0 * hn0));
      const float e1 = __expf(2.f * (ix1 + rg1 * hn1));
      const float ng0 = 1.f - 2.f / (e0 + 1.f), ng1 = 1.f - 2.f / (e1 + 1.f);
      hr0 = ng0 + zg0 * (hr0 - ng0);
      hr1 = ng1 + zg1 * (hr1 - ng1);
    }

    // ---- h(t+1) -> hbuf (MALL atomic writes) ----
    {
      char* hdst = ((t + 1) & 1) ? hs1 : hs0;
      unsigned a0 = f2bf(hr0), a1 = f2bf(hr1);
      unsigned p0 = __shfl_xor(a0, 1, 64), p1 = __shfl_xor(a1, 1, 64);
      if (!(dl & 1)) {
        st_mall_u32(hdst + rr * 1024 + ((2 * dd0) ^ SWZ(rr)), a0 | (p0 << 16));
        st_mall_u32(hdst + rr * 1024 + ((2 * dd1) ^ SWZ(rr)), a1 | (p1 << 16));
      }
    }
    // cvt x(t+1) frags in the ack shadow (compiler waits on the plain loads)
    if (t + 1 < 512) {
      xf0 = cvt8(xn0a, xn0b);
      xf1 = cvt8(xn1a, xn1b);
    }
    asm volatile("s_waitcnt vmcnt(0)" ::: "memory");  // h writes performed at MALL
    __syncthreads();  // E
    if (tid == 192) st_mall_u32(tfl + cu, tgt + 1u);  // certify h(t+1)
    if (wv == 3) ld_sys_u32(fv, fp);                  // prime next poll
  }
#undef XPART
}

// ---- logits + masked CE + accuracy; one WG per batch row ----
__global__ __launch_bounds__(128) void logits_loss(
    const unsigned short* __restrict__ hbuf, const float* __restrict__ Wout,
    const float* __restrict__ bout, const int* __restrict__ label,
    float* __restrict__ accv) {
  __shared__ float hrow[512];
  __shared__ float lg[128];
  const int b = blockIdx.x;
  const int tm = b >> 4, r = b & 15;
  const char* base = (const char*)hbuf + (size_t)tm * 16384 + r * 1024;
  for (int i = threadIdx.x; i < 256; i += 128) {
    const char* p = base + ((i * 4) ^ SWZ(r));
    unsigned v;
    asm volatile("global_load_dword %0, %1, off sc0 sc1\n\ts_waitcnt vmcnt(0)"
                 : "=v"(v) : "v"(p) : "memory");
    hrow[2 * i] = bf2f(v & 0xffffu);
    hrow[2 * i + 1] = bf2f(v >> 16);
  }
  __syncthreads();
  const int c = threadIdx.x;
  const f32x4* w4 = (const f32x4*)(Wout + (size_t)c * 512);
  const f32x4* h4 = (const f32x4*)hrow;
  float s = bout[c];
#pragma unroll 4
  for (int i = 0; i < 128; ++i) {
    f32x4 wv = w4[i], hv = h4[i];
    s += wv[0] * hv[0] + wv[1] * hv[1] + wv[2] * hv[2] + wv[3] * hv[3];
  }
  lg[c] = s;
  __syncthreads();
  if (c == 0) {
    float mx = lg[0];
    int am = 0;
    for (int i = 1; i < 128; ++i)
      if (lg[i] > mx) { mx = lg[i]; am = i; }
    float se = 0.f;
    for (int i = 0; i < 128; ++i) se += __expf(lg[i] - mx);
    const int lb = label[b];
    const float logp = lg[lb] - mx - __logf(se);
    if (lb != 0) {
      atomicAdd(&accv[0], -logp);
      atomicAdd(&accv[1], 1.0f);
    }
    if (am == lb) atomicAdd(&accv[2], 1.0f);
  }
}

__global__ void finalize_k(const float* __restrict__ accv, float* __restrict__ out) {
  out[0] = accv[0] / fmaxf(accv[1], 1.0f);
  out[1] = accv[2] * (1.0f / 256.0f);
}

extern "C" void kernel_launch(void* const* d_in, const int* in_sizes, int n_in,
                              void* d_out, int out_size, void* d_ws, size_t ws_size,
                              hipStream_t stream) {
  (void)in_sizes; (void)n_in; (void)out_size; (void)ws_size;
  const float* x = (const float*)d_in[0];
  const int* label = (const int*)d_in[1];
  const float* h0 = (const float*)d_in[2];
  const float* Wih = (const float*)d_in[3];
  const float* Whh = (const float*)d_in[4];
  const float* bih = (const float*)d_in[5];
  const float* bhh = (const float*)d_in[6];
  const float* Wout = (const float*)d_in[7];
  const float* bout = (const float*)d_in[8];
  float* out = (float*)d_out;

  char* ws = (char*)d_ws;
  unsigned* flags = (unsigned*)ws;                      // 16 teams x 32 u32 (16 used)
  float* accv = (float*)(ws + 4096);                    // 3 accumulators
  unsigned short* hbuf = (unsigned short*)(ws + 8192);  // 2 slots x 16 teams x 16 KB

  hipMemsetAsync(ws, 0, 8192, stream);  // flags + accv: deterministic per call

  gru_persistent<<<dim3(256), dim3(256), 0, stream>>>(x, h0, Wih, Whh, bih, bhh,
                                                      flags, hbuf);
  logits_loss<<<dim3(256), dim3(128), 0, stream>>>(hbuf, Wout, bout, label, accv);
  finalize_k<<<dim3(1), dim3(1), 0, stream>>>(accv, out);
}

// Round 18
// 1223.047 us; speedup vs baseline: 1.5796x; 1.0105x over previous
//
#include <hip/hip_runtime.h>
#include <hip/hip_bf16.h>
#include <stdint.h>

// GRU: B=256, S=512, E=256, H=512, C=128 — FINAL (R14 skeleton, proven 1226us,
// absmax 0.0; R15/R16/R17 falsified and reverted).
// 16 teams x 16 WGs (tm = wg&15, cu = wg>>4). Team covers batch rows
// [16tm,16tm+16); member cu owns h dims [32cu,32cu+32). 4 waves/WG split the
// fused K=768 of [x_t | h] @ [W_ih|W_hh]^T; W slice in VGPRs (144/lane).
// Protocol: sc0 sc1 device-scope via MALL; 16 flags/team on ONE 64B line;
// wave-3 single-load poll (pipelined polls BANNED — R12 regalloc fault);
// barriers A/D/E (barE is load-bearing — R16); direct h-frag gathers (R13);
// returnless atomic-swap protocol writes (R14: ack at MALL perform-point).
// Structural wall: 512 serial all-to-all rounds; ~5700cy/step = ack(~900) +
// flag prop+detect(~1400-1800) + gather RT(~900) + compute/barriers(~1900).

typedef __attribute__((ext_vector_type(8))) short bf16x8;
typedef __attribute__((ext_vector_type(4))) float f32x4;

#define SWZ(r) (((r)&7) << 4)

static __device__ __forceinline__ unsigned short f2bf(float f) {
  unsigned x = __builtin_bit_cast(unsigned, f);
  return (unsigned short)((x + 0x7fffu + ((x >> 16) & 1u)) >> 16);  // RNE
}
static __device__ __forceinline__ float bf2f(unsigned u) {
  return __builtin_bit_cast(float, u << 16);
}
// Protocol write: returnless device-scope atomic swap — ack at MALL
// perform-point (~400cy earlier than store-through ack, R14-measured).
static __device__ __forceinline__ void st_mall_u32(void* p, unsigned v) {
  asm volatile("global_atomic_swap %0, %1, off" :: "v"(p), "v"(v) : "memory");
}
static __device__ __forceinline__ void ld_sys_u32(unsigned& d, const void* p) {
  asm volatile("global_load_dword %0, %1, off sc0 sc1" : "=v"(d) : "v"(p) : "memory");
}
static __device__ __forceinline__ bf16x8 cvt8(f32x4 a, f32x4 b) {
  bf16x8 r;
#pragma unroll
  for (int q = 0; q < 4; ++q) {
    r[q] = (short)f2bf(a[q]);
    r[4 + q] = (short)f2bf(b[q]);
  }
  return r;
}

__global__ __launch_bounds__(256, 1) void gru_persistent(
    const float* __restrict__ x, const float* __restrict__ h0,
    const float* __restrict__ Wih, const float* __restrict__ Whh,
    const float* __restrict__ bih, const float* __restrict__ bhh,
    unsigned* __restrict__ flags, unsigned short* __restrict__ hbuf) {
  __shared__ __align__(16) float cb[4 * 4 * 2 * 256];  // [wave][type][nf][row*16+col]

  const int tid = threadIdx.x, wg = blockIdx.x;
  const int tm = wg & 15, cu = wg >> 4;
  const int wv = tid >> 6, ln = tid & 63;
  const int bm = tm << 4;   // batch base
  const int d0 = cu << 5;   // h-dim slice base (32 dims)

  unsigned* tfl = flags + tm * 32;       // 16 flags on one 64B line; teams 128B apart
  const unsigned* fp = tfl + (ln & 15);
  char* hs0 = (char*)hbuf + (size_t)tm * 16384;
  char* hs1 = (char*)hbuf + 262144 + (size_t)tm * 16384;

  // ---- W slice -> VGPR bf16 B-frags (once); frag f: 0-1 = x-part, 2-5 = h-part ----
  bf16x8 BF[3][2][6];
  {
    const int j = ln & 15, kgw = ln >> 4;
#pragma unroll
    for (int g = 0; g < 3; ++g)
#pragma unroll
      for (int nf = 0; nf < 2; ++nf)
#pragma unroll
        for (int f = 0; f < 6; ++f) {
          const int R = g * 512 + d0 + nf * 16 + j;
          const float* src;
          if (f < 2) src = Wih + (size_t)R * 256 + (64 * wv + 32 * f + 8 * kgw);
          else       src = Whh + (size_t)R * 512 + (128 * wv + 32 * (f - 2) + 8 * kgw);
          bf16x8 v;
#pragma unroll
          for (int i = 0; i < 8; ++i) v[i] = (short)f2bf(src[i]);
          BF[g][nf][f] = v;
        }
  }

  const int dl = tid & 15, rr = tid >> 4;
  const int dd0 = d0 + dl, dd1 = d0 + 16 + dl;
  const float bR0 = bih[dd0] + bhh[dd0], bR1 = bih[dd1] + bhh[dd1];
  const float bZ0 = bih[512 + dd0] + bhh[512 + dd0], bZ1 = bih[512 + dd1] + bhh[512 + dd1];
  const float bNx0 = bih[1024 + dd0], bNx1 = bih[1024 + dd1];
  const float bNh0 = bhh[1024 + dd0], bNh1 = bhh[1024 + dd1];

  float hr0 = h0[(size_t)(bm + rr) * 512 + dd0];
  float hr1 = h0[(size_t)(bm + rr) * 512 + dd1];

  // ---- gather geometry (loop-invariant): lane covers A-row (ln&15), k-chunk kg ----
  const int grow = ln & 15, kg = ln >> 4;
  const int gof0 = grow * 1024 + ((256 * wv + 0 + 16 * kg) ^ SWZ(grow));
  const int gof1 = grow * 1024 + ((256 * wv + 64 + 16 * kg) ^ SWZ(grow));
  const int gof2 = grow * 1024 + ((256 * wv + 128 + 16 * kg) ^ SWZ(grow));
  const int gof3 = grow * 1024 + ((256 * wv + 192 + 16 * kg) ^ SWZ(grow));
  // x frag base: row (bm+grow), floats [64wv+8kg .. ) ; frag fx adds 32*fx
  const float* xlane = x + (size_t)(bm + grow) * 512 * 256 + 64 * wv + 8 * kg;

  // ---- prologue: h(0) -> slot0 (MALL writes); x(0) -> regs -> bf16 frags ----
  {
    unsigned a0 = f2bf(hr0), a1 = f2bf(hr1);
    unsigned p0 = __shfl_xor(a0, 1, 64), p1 = __shfl_xor(a1, 1, 64);
    if (!(dl & 1)) {
      st_mall_u32(hs0 + rr * 1024 + ((2 * dd0) ^ SWZ(rr)), a0 | (p0 << 16));
      st_mall_u32(hs0 + rr * 1024 + ((2 * dd1) ^ SWZ(rr)), a1 | (p1 << 16));
    }
  }
  f32x4 xn0a = *(const f32x4*)(xlane + 0);
  f32x4 xn0b = *(const f32x4*)(xlane + 4);
  f32x4 xn1a = *(const f32x4*)(xlane + 32);
  f32x4 xn1b = *(const f32x4*)(xlane + 36);
  bf16x8 xf0 = cvt8(xn0a, xn0b);
  bf16x8 xf1 = cvt8(xn1a, xn1b);

  asm volatile("s_waitcnt vmcnt(0)" ::: "memory");  // h0 writes performed at MALL
  __syncthreads();                                  // E0
  if (tid == 192) st_mall_u32(tfl + cu, 1u);        // certify h(0)
  unsigned fv = 0;
  if (wv == 3) ld_sys_u32(fv, fp);                  // prime first poll

  for (int t = 0; t < 512; ++t) {
    const unsigned tgt = (unsigned)(t + 1);
    f32x4 aR[2] = {}, aZ[2] = {}, aNx[2] = {}, aNh[2] = {};

    // x-part MFMA from register frags (per-acc order fx0 then fx1)
#define XPART()                                                                          \
  {                                                                                      \
    _Pragma("unroll")                                                                    \
    for (int nf = 0; nf < 2; ++nf) {                                                     \
      aR[nf]  = __builtin_amdgcn_mfma_f32_16x16x32_bf16(xf0, BF[0][nf][0], aR[nf], 0, 0, 0);  \
      aZ[nf]  = __builtin_amdgcn_mfma_f32_16x16x32_bf16(xf0, BF[1][nf][0], aZ[nf], 0, 0, 0);  \
      aNx[nf] = __builtin_amdgcn_mfma_f32_16x16x32_bf16(xf0, BF[2][nf][0], aNx[nf], 0, 0, 0); \
      aR[nf]  = __builtin_amdgcn_mfma_f32_16x16x32_bf16(xf1, BF[0][nf][1], aR[nf], 0, 0, 0);  \
      aZ[nf]  = __builtin_amdgcn_mfma_f32_16x16x32_bf16(xf1, BF[1][nf][1], aZ[nf], 0, 0, 0);  \
      aNx[nf] = __builtin_amdgcn_mfma_f32_16x16x32_bf16(xf1, BF[2][nf][1], aNx[nf], 0, 0, 0); \
    }                                                                                    \
  }

    if (wv == 3) {
      // single-load poll (R10-proven; drain prime, then load+wait per round)
      asm volatile("s_waitcnt vmcnt(0)" : "+v"(fv) :: "memory");
      while (__ballot(fv >= tgt) != ~0ull) {
        asm volatile("global_load_dword %0, %1, off sc0 sc1\n\ts_waitcnt vmcnt(0)"
                     : "=v"(fv) : "v"(fp) : "memory");
      }
    } else {
      XPART();  // waves 0-2: x-MFMA under the poll
    }
    __syncthreads();  // A: h(t) certified for the whole WG

    // ---- direct h-frag gathers (device-scope): regs, no LDS hop ----
    const char* hsrc = (t & 1) ? hs1 : hs0;
    f32x4 g0, g1, g2, g3;
    asm volatile("global_load_dwordx4 %0, %1, off sc0 sc1"
                 : "=v"(g0) : "v"(hsrc + gof0) : "memory");
    asm volatile("global_load_dwordx4 %0, %1, off sc0 sc1"
                 : "=v"(g1) : "v"(hsrc + gof1) : "memory");
    asm volatile("global_load_dwordx4 %0, %1, off sc0 sc1"
                 : "=v"(g2) : "v"(hsrc + gof2) : "memory");
    asm volatile("global_load_dwordx4 %0, %1, off sc0 sc1"
                 : "=v"(g3) : "v"(hsrc + gof3) : "memory");

    if (wv == 3) { XPART(); }  // wave 3: x-MFMA under its own gather RT
    __builtin_amdgcn_sched_barrier(0);  // pin x-MFMA BEFORE the drain

    asm volatile("s_waitcnt vmcnt(0)"
                 : "+v"(g0), "+v"(g1), "+v"(g2), "+v"(g3) :: "memory");
    const bf16x8 hf0 = __builtin_bit_cast(bf16x8, g0);
    const bf16x8 hf1 = __builtin_bit_cast(bf16x8, g1);
    const bf16x8 hf2 = __builtin_bit_cast(bf16x8, g2);
    const bf16x8 hf3 = __builtin_bit_cast(bf16x8, g3);

    // x(t+1) prefetch (plain loads; compiler-managed waits; consumed at tail cvt)
    if (t + 1 < 512) {
      const float* xb2 = xlane + (size_t)(t + 1) * 256;
      xn0a = *(const f32x4*)(xb2 + 0);
      xn0b = *(const f32x4*)(xb2 + 4);
      xn1a = *(const f32x4*)(xb2 + 32);
      xn1b = *(const f32x4*)(xb2 + 36);
    }

    // ---- h-part MFMA (4 frags, register operands; per-acc order fh0..3) ----
#pragma unroll
    for (int nf = 0; nf < 2; ++nf) {
      aR[nf]  = __builtin_amdgcn_mfma_f32_16x16x32_bf16(hf0, BF[0][nf][2], aR[nf], 0, 0, 0);
      aZ[nf]  = __builtin_amdgcn_mfma_f32_16x16x32_bf16(hf0, BF[1][nf][2], aZ[nf], 0, 0, 0);
      aNh[nf] = __builtin_amdgcn_mfma_f32_16x16x32_bf16(hf0, BF[2][nf][2], aNh[nf], 0, 0, 0);
      aR[nf]  = __builtin_amdgcn_mfma_f32_16x16x32_bf16(hf1, BF[0][nf][3], aR[nf], 0, 0, 0);
      aZ[nf]  = __builtin_amdgcn_mfma_f32_16x16x32_bf16(hf1, BF[1][nf][3], aZ[nf], 0, 0, 0);
      aNh[nf] = __builtin_amdgcn_mfma_f32_16x16x32_bf16(hf1, BF[2][nf][3], aNh[nf], 0, 0, 0);
      aR[nf]  = __builtin_amdgcn_mfma_f32_16x16x32_bf16(hf2, BF[0][nf][4], aR[nf], 0, 0, 0);
      aZ[nf]  = __builtin_amdgcn_mfma_f32_16x16x32_bf16(hf2, BF[1][nf][4], aZ[nf], 0, 0, 0);
      aNh[nf] = __builtin_amdgcn_mfma_f32_16x16x32_bf16(hf2, BF[2][nf][4], aNh[nf], 0, 0, 0);
      aR[nf]  = __builtin_amdgcn_mfma_f32_16x16x32_bf16(hf3, BF[0][nf][5], aR[nf], 0, 0, 0);
      aZ[nf]  = __builtin_amdgcn_mfma_f32_16x16x32_bf16(hf3, BF[1][nf][5], aZ[nf], 0, 0, 0);
      aNh[nf] = __builtin_amdgcn_mfma_f32_16x16x32_bf16(hf3, BF[2][nf][5], aNh[nf], 0, 0, 0);
    }

    // ---- partials -> cbuf ----
    {
      const int cc = ln & 15, cg = ln >> 4;
#pragma unroll
      for (int nf = 0; nf < 2; ++nf)
#pragma unroll
        for (int i = 0; i < 4; ++i) {
          const int row = cg * 4 + i;
          cb[((wv * 4 + 0) * 2 + nf) * 256 + row * 16 + cc] = aR[nf][i];
          cb[((wv * 4 + 1) * 2 + nf) * 256 + row * 16 + cc] = aZ[nf][i];
          cb[((wv * 4 + 2) * 2 + nf) * 256 + row * 16 + cc] = aNx[nf][i];
          cb[((wv * 4 + 3) * 2 + nf) * 256 + row * 16 + cc] = aNh[nf][i];
        }
    }
    __syncthreads();  // D

    // ---- combine + gates (fp32) ----
    {
#define CBX(w, ty, nf) cb[(((w) * 4 + (ty)) * 2 + (nf)) * 256 + rr * 16 + dl]
      float rp0 = bR0 + CBX(0,0,0) + CBX(1,0,0) + CBX(2,0,0) + CBX(3,0,0);
      float rp1 = bR1 + CBX(0,0,1) + CBX(1,0,1) + CBX(2,0,1) + CBX(3,0,1);
      float zp0 = bZ0 + CBX(0,1,0) + CBX(1,1,0) + CBX(2,1,0) + CBX(3,1,0);
      float zp1 = bZ1 + CBX(0,1,1) + CBX(1,1,1) + CBX(2,1,1) + CBX(3,1,1);
      float ix0 = bNx0 + CBX(0,2,0) + CBX(1,2,0) + CBX(2,2,0) + CBX(3,2,0);
      float ix1 = bNx1 + CBX(0,2,1) + CBX(1,2,1) + CBX(2,2,1) + CBX(3,2,1);
      float hn0 = bNh0 + CBX(0,3,0) + CBX(1,3,0) + CBX(2,3,0) + CBX(3,3,0);
      float hn1 = bNh1 + CBX(0,3,1) + CBX(1,3,1) + CBX(2,3,1) + CBX(3,3,1);
#undef CBX
      const float rg0 = 1.f / (1.f + __expf(-rp0)), rg1 = 1.f / (1.f + __expf(-rp1));
      const float zg0 = 1.f / (1.f + __expf(-zp0)), zg1 = 1.f / (1.f + __expf(-zp1));
      const float e0 = __expf(2.f * (ix0 + rg0 * hn0));
      const float e1 = __expf(2.f * (ix1 + rg1 * hn1));
      const float ng0 = 1.f - 2.f / (e0 + 1.f), ng1 = 1.f - 2.f / (e1 + 1.f);
      hr0 = ng0 + zg0 * (hr0 - ng0);
      hr1 = ng1 + zg1 * (hr1 - ng1);
    }

    // ---- h(t+1) -> hbuf (MALL atomic writes) ----
    {
      char* hdst = ((t + 1) & 1) ? hs1 : hs0;
      unsigned a0 = f2bf(hr0), a1 = f2bf(hr1);
      unsigned p0 = __shfl_xor(a0, 1, 64), p1 = __shfl_xor(a1, 1, 64);
      if (!(dl & 1)) {
        st_mall_u32(hdst + rr * 1024 + ((2 * dd0) ^ SWZ(rr)), a0 | (p0 << 16));
        st_mall_u32(hdst + rr * 1024 + ((2 * dd1) ^ SWZ(rr)), a1 | (p1 << 16));
      }
    }
    // cvt x(t+1) frags in the ack shadow (compiler waits on the plain loads)
    if (t + 1 < 512) {
      xf0 = cvt8(xn0a, xn0b);
      xf1 = cvt8(xn1a, xn1b);
    }
    asm volatile("s_waitcnt vmcnt(0)" ::: "memory");  // h writes performed at MALL
    __syncthreads();  // E
    if (tid == 192) st_mall_u32(tfl + cu, tgt + 1u);  // certify h(t+1)
    if (wv == 3) ld_sys_u32(fv, fp);                  // prime next poll
  }
#undef XPART
}

// ---- logits + masked CE + accuracy; one WG per batch row ----
__global__ __launch_bounds__(128) void logits_loss(
    const unsigned short* __restrict__ hbuf, const float* __restrict__ Wout,
    const float* __restrict__ bout, const int* __restrict__ label,
    float* __restrict__ accv) {
  __shared__ float hrow[512];
  __shared__ float lg[128];
  const int b = blockIdx.x;
  const int tm = b >> 4, r = b & 15;
  const char* base = (const char*)hbuf + (size_t)tm * 16384 + r * 1024;
  for (int i = threadIdx.x; i < 256; i += 128) {
    const char* p = base + ((i * 4) ^ SWZ(r));
    unsigned v;
    asm volatile("global_load_dword %0, %1, off sc0 sc1\n\ts_waitcnt vmcnt(0)"
                 : "=v"(v) : "v"(p) : "memory");
    hrow[2 * i] = bf2f(v & 0xffffu);
    hrow[2 * i + 1] = bf2f(v >> 16);
  }
  __syncthreads();
  const int c = threadIdx.x;
  const f32x4* w4 = (const f32x4*)(Wout + (size_t)c * 512);
  const f32x4* h4 = (const f32x4*)hrow;
  float s = bout[c];
#pragma unroll 4
  for (int i = 0; i < 128; ++i) {
    f32x4 wv = w4[i], hv = h4[i];
    s += wv[0] * hv[0] + wv[1] * hv[1] + wv[2] * hv[2] + wv[3] * hv[3];
  }
  lg[c] = s;
  __syncthreads();
  if (c == 0) {
    float mx = lg[0];
    int am = 0;
    for (int i = 1; i < 128; ++i)
      if (lg[i] > mx) { mx = lg[i]; am = i; }
    float se = 0.f;
    for (int i = 0; i < 128; ++i) se += __expf(lg[i] - mx);
    const int lb = label[b];
    const float logp = lg[lb] - mx - __logf(se);
    if (lb != 0) {
      atomicAdd(&accv[0], -logp);
      atomicAdd(&accv[1], 1.0f);
    }
    if (am == lb) atomicAdd(&accv[2], 1.0f);
  }
}

__global__ void finalize_k(const float* __restrict__ accv, float* __restrict__ out) {
  out[0] = accv[0] / fmaxf(accv[1], 1.0f);
  out[1] = accv[2] * (1.0f / 256.0f);
}

extern "C" void kernel_launch(void* const* d_in, const int* in_sizes, int n_in,
                              void* d_out, int out_size, void* d_ws, size_t ws_size,
                              hipStream_t stream) {
  (void)in_sizes; (void)n_in; (void)out_size; (void)ws_size;
  const float* x = (const float*)d_in[0];
  const int* label = (const int*)d_in[1];
  const float* h0 = (const float*)d_in[2];
  const float* Wih = (const float*)d_in[3];
  const float* Whh = (const float*)d_in[4];
  const float* bih = (const float*)d_in[5];
  const float* bhh = (const float*)d_in[6];
  const float* Wout = (const float*)d_in[7];
  const float* bout = (const float*)d_in[8];
  float* out = (float*)d_out;

  char* ws = (char*)d_ws;
  unsigned* flags = (unsigned*)ws;                      // 16 teams x 32 u32 (16 used)
  float* accv = (float*)(ws + 4096);                    // 3 accumulators
  unsigned short* hbuf = (unsigned short*)(ws + 8192);  // 2 slots x 16 teams x 16 KB

  hipMemsetAsync(ws, 0, 8192, stream);  // flags + accv: deterministic per call

  gru_persistent<<<dim3(256), dim3(256), 0, stream>>>(x, h0, Wih, Whh, bih, bhh,
                                                      flags, hbuf);
  logits_loss<<<dim3(256), dim3(128), 0, stream>>>(hbuf, Wout, bout, label, accv);
  finalize_k<<<dim3(1), dim3(1), 0, stream>>>(accv, out);
}